// Round 5
// baseline (186.953 us; speedup 1.0000x reference)
//
#include <hip/hip_runtime.h>

// ACmix: b=2, C=64 (HEAD=4 x HEAD_DIM=16), (d,w,h)=(8,32,32), L=8192
// Attention view: (H2,W2)=(64,128). Conv view: (8, 1024). K_ATT=7 PAD=3.
//
// Structure (R5): 2 dispatches.
//   qkvf_kernel : x -> q(pre-scaled by 0.25), k, v, f   (as R4 + q scaling)
//   fused_kernel: per (b, head, 16x16 tile) block computes BOTH the
//                 attention branch and the depthwise-conv branch for its own
//                 16 channels x 256 pixels, writing out exactly once
//                 (no RMW, no race, one fewer dispatch).
//                 LDS is a union: phase A kp/vt (77.4 KB), phase B fs
//                 (82.9 KB f-halo), separated by barriers.

// ---------------------------------------------------------------------------
// Kernel 1: fused q/k/v 1x1 convs + fc (f_all).
// ---------------------------------------------------------------------------
__global__ __launch_bounds__(512) void qkvf_kernel(
    const float* __restrict__ x,
    const float* __restrict__ w1, const float* __restrict__ b1,
    const float* __restrict__ w2, const float* __restrict__ b2,
    const float* __restrict__ w3, const float* __restrict__ b3,
    const float* __restrict__ wfc,
    float* __restrict__ q, float* __restrict__ k, float* __restrict__ v,
    float* __restrict__ f)
{
    __shared__ float xs[64][64];        // [ci][l]       16 KB
    __shared__ float wlds[3][64][64];   // [mat][c][ci]  48 KB

    int bx    = blockIdx.x;
    int ltile = bx & 127;
    int b     = bx >> 7;
    int l0    = ltile * 64;

    {
        float4* wl = (float4*)wlds;
        for (int t = threadIdx.x; t < 3072; t += 512) {
            int m   = t >> 10;
            int idx = t & 1023;
            const float* src = (m == 0) ? w1 : (m == 1) ? w2 : w3;
            wl[t] = ((const float4*)src)[idx];
        }
    }
    const float4* xg = (const float4*)(x + (size_t)b * 64 * 8192);
    for (int t = threadIdx.x; t < 1024; t += 512) {
        int ci = t >> 4, col = t & 15;
        *((float4*)&xs[ci][col * 4]) = xg[ci * 2048 + (l0 >> 2) + col];
    }
    __syncthreads();

    int lane = threadIdx.x & 63;
    int wv   = __builtin_amdgcn_readfirstlane(threadIdx.x >> 6);
    int l    = l0 + lane;
    int hd0  = 2 * wv;

    float qa[4][2], ka[4][2], va[4][2];
#pragma unroll
    for (int hh = 0; hh < 4; ++hh)
#pragma unroll
        for (int p = 0; p < 2; ++p) {
            int c = hh * 16 + hd0 + p;
            qa[hh][p] = b1[c]; ka[hh][p] = b2[c]; va[hh][p] = b3[c];
        }

#pragma unroll 4
    for (int c4 = 0; c4 < 16; ++c4) {
        float xv[4];
#pragma unroll
        for (int u = 0; u < 4; ++u) xv[u] = xs[c4 * 4 + u][lane];
#pragma unroll
        for (int hh = 0; hh < 4; ++hh)
#pragma unroll
            for (int p = 0; p < 2; ++p) {
                int c = hh * 16 + hd0 + p;
                float4 wq = *(const float4*)&wlds[0][c][c4 * 4];
                float4 wk = *(const float4*)&wlds[1][c][c4 * 4];
                float4 wx = *(const float4*)&wlds[2][c][c4 * 4];
                qa[hh][p] = fmaf(wq.x, xv[0], qa[hh][p]);
                qa[hh][p] = fmaf(wq.y, xv[1], qa[hh][p]);
                qa[hh][p] = fmaf(wq.z, xv[2], qa[hh][p]);
                qa[hh][p] = fmaf(wq.w, xv[3], qa[hh][p]);
                ka[hh][p] = fmaf(wk.x, xv[0], ka[hh][p]);
                ka[hh][p] = fmaf(wk.y, xv[1], ka[hh][p]);
                ka[hh][p] = fmaf(wk.z, xv[2], ka[hh][p]);
                ka[hh][p] = fmaf(wk.w, xv[3], ka[hh][p]);
                va[hh][p] = fmaf(wx.x, xv[0], va[hh][p]);
                va[hh][p] = fmaf(wx.y, xv[1], va[hh][p]);
                va[hh][p] = fmaf(wx.z, xv[2], va[hh][p]);
                va[hh][p] = fmaf(wx.w, xv[3], va[hh][p]);
            }
    }

#pragma unroll
    for (int hh = 0; hh < 4; ++hh)
#pragma unroll
        for (int p = 0; p < 2; ++p) {
            int c = hh * 16 + hd0 + p;
            size_t o = (size_t)(b * 64 + c) * 8192 + l;
            q[o] = qa[hh][p] * 0.25f;   // fold HEAD_DIM^-0.5 here
            k[o] = ka[hh][p]; v[o] = va[hh][p];
        }

#pragma unroll
    for (int m = 0; m < 9; ++m)
#pragma unroll
        for (int p = 0; p < 2; ++p) {
            float acc = 0.f;
#pragma unroll
            for (int hh = 0; hh < 4; ++hh) {
                acc = fmaf(wfc[m * 12 + 0 + hh], qa[hh][p], acc);
                acc = fmaf(wfc[m * 12 + 4 + hh], ka[hh][p], acc);
                acc = fmaf(wfc[m * 12 + 8 + hh], va[hh][p], acc);
            }
            int hd = hd0 + p;
            f[((size_t)(b * 9 + m) * 16 + hd) * 8192 + l] = acc;
        }
}

// ---------------------------------------------------------------------------
// Kernel 2: fused attention + conv branch, single writer of out.
// Block = (b, head, yt, xt): 16x16 pixel tile, 256 threads, grid 256.
// Phase A: kp/vt in smem ([22][22][20] each, pad 20 = conflict-min b128).
// Phase B: fs = f halo [c36][y2r:4][s:8][xo:18] (82,944 B) unioned over A.
//   Pixel l: y2 = l>>10 = y>>3, x2 = l&1023 = (y&7)*128 + x.  3x3 conv
//   neighbors: y2+-1 (4 staged d-rows), x2+-1 (18 staged cols per strip).
// out[c][l] = rate1/se * att_acc + rate2 * (conv_acc + bdep).
// ---------------------------------------------------------------------------
__global__ __launch_bounds__(256) void fused_kernel(
    const float* __restrict__ q, const float* __restrict__ k,
    const float* __restrict__ v, const float* __restrict__ f,
    const float* __restrict__ wp, const float* __restrict__ bp,
    const float* __restrict__ wdep, const float* __restrict__ bdep,
    const float* __restrict__ rate1p, const float* __restrict__ rate2p,
    float* __restrict__ out)
{
    __shared__ float smem[20736];          // 82,944 B (union of phases)
    float* kp = smem;                      // [22][22][20] = 9680 floats
    float* vt = smem + 9680;               // [22][22][20]

    int bx = blockIdx.x;          // 8 n * 4 yt * 8 xt = 256
    int xt = bx & 7;
    int yt = (bx >> 3) & 3;
    int n  = bx >> 5;
    int head = n & 3;
    int b    = n >> 2;
    int y0 = yt * 16, x0 = xt * 16;

    // ================= phase A: stage kp (= k - pe) and vt =================
    const int NELEM = 16 * 22 * 22;   // c slow; ty, tx fast
    for (int e = threadIdx.x; e < NELEM; e += 256) {
        int tx  = e % 22;
        int rem = e / 22;
        int ty  = rem % 22;
        int c   = rem / 22;
        int sy = y0 + ty - 3; if (sy < 0) sy = -sy; else if (sy >= 64)  sy = 126 - sy;
        int sx = x0 + tx - 3; if (sx < 0) sx = -sx; else if (sx >= 128) sx = 254 - sx;
        int l = sy * 128 + sx;
        size_t o = (size_t)(b * 64 + head * 16 + c) * 8192 + l;
        int dd = l >> 10, r2 = l & 1023, ww = r2 >> 5, hh = r2 & 31;
        float ld = dd * (2.0f / 7.0f)  - 1.0f;
        float lw = ww * (2.0f / 31.0f) - 1.0f;
        float lh = hh * (2.0f / 31.0f) - 1.0f;
        float pe = bp[c];
        pe = fmaf(wp[c * 3 + 0], ld, pe);
        pe = fmaf(wp[c * 3 + 1], lw, pe);
        pe = fmaf(wp[c * 3 + 2], lh, pe);
        int li = (ty * 22 + tx) * 20 + c;
        kp[li] = k[o] - pe;
        vt[li] = v[o];
    }
    __syncthreads();

    // ================= attention compute =================
    int tx = threadIdx.x & 15, ty = threadIdx.x >> 4;
    int l = (y0 + ty) * 128 + (x0 + tx);

    float qc[16];
#pragma unroll
    for (int c = 0; c < 16; ++c)
        qc[c] = q[(size_t)(b * 64 + head * 16 + c) * 8192 + l]; // pre-scaled

    float lg[49];
#pragma unroll
    for (int i = 0; i < 7; ++i)
#pragma unroll
        for (int j = 0; j < 7; ++j) {
            const float4* p = (const float4*)&kp[((ty + i) * 22 + tx + j) * 20];
            float4 a = p[0], b4 = p[1], c4 = p[2], d4 = p[3];
            float acc =      qc[0]  * a.x;
            acc = fmaf(qc[1],  a.y,  acc); acc = fmaf(qc[2],  a.z,  acc);
            acc = fmaf(qc[3],  a.w,  acc); acc = fmaf(qc[4],  b4.x, acc);
            acc = fmaf(qc[5],  b4.y, acc); acc = fmaf(qc[6],  b4.z, acc);
            acc = fmaf(qc[7],  b4.w, acc); acc = fmaf(qc[8],  c4.x, acc);
            acc = fmaf(qc[9],  c4.y, acc); acc = fmaf(qc[10], c4.z, acc);
            acc = fmaf(qc[11], c4.w, acc); acc = fmaf(qc[12], d4.x, acc);
            acc = fmaf(qc[13], d4.y, acc); acc = fmaf(qc[14], d4.z, acc);
            acc = fmaf(qc[15], d4.w, acc);
            lg[i * 7 + j] = acc;
        }

    float mx = lg[0];
#pragma unroll
    for (int kk = 1; kk < 49; ++kk) mx = fmaxf(mx, lg[kk]);
    float se = 0.f;
#pragma unroll
    for (int kk = 0; kk < 49; ++kk) { lg[kk] = __expf(lg[kk] - mx); se += lg[kk]; }
    float scale = rate1p[0] / se;

    float oc[16];
#pragma unroll
    for (int c = 0; c < 16; ++c) oc[c] = 0.f;
#pragma unroll
    for (int i = 0; i < 7; ++i)
#pragma unroll
        for (int j = 0; j < 7; ++j) {
            float wgt = lg[i * 7 + j];
            const float4* p = (const float4*)&vt[((ty + i) * 22 + tx + j) * 20];
            float4 a = p[0], b4 = p[1], c4 = p[2], d4 = p[3];
            oc[0]  = fmaf(wgt, a.x,  oc[0]);  oc[1]  = fmaf(wgt, a.y,  oc[1]);
            oc[2]  = fmaf(wgt, a.z,  oc[2]);  oc[3]  = fmaf(wgt, a.w,  oc[3]);
            oc[4]  = fmaf(wgt, b4.x, oc[4]);  oc[5]  = fmaf(wgt, b4.y, oc[5]);
            oc[6]  = fmaf(wgt, b4.z, oc[6]);  oc[7]  = fmaf(wgt, b4.w, oc[7]);
            oc[8]  = fmaf(wgt, c4.x, oc[8]);  oc[9]  = fmaf(wgt, c4.y, oc[9]);
            oc[10] = fmaf(wgt, c4.z, oc[10]); oc[11] = fmaf(wgt, c4.w, oc[11]);
            oc[12] = fmaf(wgt, d4.x, oc[12]); oc[13] = fmaf(wgt, d4.y, oc[13]);
            oc[14] = fmaf(wgt, d4.z, oc[14]); oc[15] = fmaf(wgt, d4.w, oc[15]);
        }

    __syncthreads();   // all kp/vt reads done before smem is re-used

    // ================= phase B: stage f halo =================
    // fs[c36][y2r(4)][s(8)][xo(18)]; linear = ((c36*4+y2r)*8+s)*18+xo
    // global: ch = 36*head + c36; y2 = (y0>>3)-1+y2r; x2 = s*128 + x0-1+xo
    float* fs = smem;
    const int NF = 36 * 4 * 8 * 18;        // 20736
    const float* fb = f + (size_t)(b * 144 + 36 * head) * 8192;
    int y2base = (y0 >> 3) - 1;
    for (int e = threadIdx.x; e < NF; e += 256) {
        int xo  = e % 18;
        int r   = e / 18;
        int s   = r & 7;
        int r2  = r >> 3;
        int y2r = r2 & 3;
        int c36 = r2 >> 2;
        int y2  = y2base + y2r;
        int x2  = s * 128 + x0 - 1 + xo;
        float val = 0.f;
        if (y2 >= 0 && y2 < 8 && x2 >= 0 && x2 < 1024)
            val = fb[(size_t)c36 * 8192 + y2 * 1024 + x2];
        fs[e] = val;
    }
    __syncthreads();

    // ================= conv compute + combined store =================
    int s    = ty & 7;            // pixel strip (y0 multiple of 16)
    int y2rp = 1 + (ty >> 3);     // staged row of the pixel's y2
    int xop  = tx + 1;            // staged col of the pixel's x2

    float cacc[16];
#pragma unroll
    for (int cc = 0; cc < 16; ++cc) cacc[cc] = 0.f;

#pragma unroll 1
    for (int i = 0; i < 9; ++i) {
#pragma unroll
        for (int ky = 0; ky < 3; ++ky)
#pragma unroll
            for (int kx = 0; kx < 3; ++kx) {
                // 4 group reads serve 4 consecutive cc each
                float fv[4];
#pragma unroll
                for (int grp = 0; grp < 4; ++grp) {
                    int c36 = grp * 9 + i;
                    fv[grp] = fs[((c36 * 4 + y2rp + ky - 1) * 8 + s) * 18
                                 + xop + kx - 1];
                }
#pragma unroll
                for (int cc = 0; cc < 16; ++cc) {
                    int o = head * 16 + cc;
                    float wv = wdep[((o * 9 + i) * 3 + ky) * 3 + kx];
                    cacc[cc] = fmaf(wv, fv[cc >> 2], cacc[cc]);
                }
            }
    }

    float rate2 = rate2p[0];
#pragma unroll
    for (int cc = 0; cc < 16; ++cc) {
        float bd = bdep[head * 16 + cc];
        out[(size_t)(b * 64 + head * 16 + cc) * 8192 + l]
            = oc[cc] * scale + rate2 * (cacc[cc] + bd);
    }
}

// ---------------------------------------------------------------------------
extern "C" void kernel_launch(void* const* d_in, const int* in_sizes, int n_in,
                              void* d_out, int out_size, void* d_ws, size_t ws_size,
                              hipStream_t stream)
{
    (void)in_sizes; (void)n_in; (void)out_size; (void)ws_size;
    const float* x     = (const float*)d_in[0];
    const float* w1    = (const float*)d_in[1];
    const float* b1    = (const float*)d_in[2];
    const float* w2    = (const float*)d_in[3];
    const float* b2    = (const float*)d_in[4];
    const float* w3    = (const float*)d_in[5];
    const float* b3    = (const float*)d_in[6];
    const float* wp    = (const float*)d_in[7];
    const float* bp    = (const float*)d_in[8];
    const float* wfc   = (const float*)d_in[9];
    const float* wdep  = (const float*)d_in[10];
    const float* bdep  = (const float*)d_in[11];
    const float* rate1 = (const float*)d_in[12];
    const float* rate2 = (const float*)d_in[13];
    float* out = (float*)d_out;

    float* wsf = (float*)d_ws;
    float* q = wsf;                 // 3 x 1,048,576 floats (q,k,v)
    float* k = wsf + 1048576;
    float* v = wsf + 2097152;
    float* f = wsf + 3145728;       // 2,359,296 floats

    qkvf_kernel <<<256, 512, 0, stream>>>(x, w1, b1, w2, b2, w3, b3, wfc,
                                          q, k, v, f);
    fused_kernel<<<256, 256, 0, stream>>>(q, k, v, f, wp, bp, wdep, bdep,
                                          rate1, rate2, out);
}

// Round 6
// 127.130 us; speedup vs baseline: 1.4706x; 1.4706x over previous
//
#include <hip/hip_runtime.h>

// ACmix: b=2, C=64 (HEAD=4 x HEAD_DIM=16), (d,w,h)=(8,32,32), L=8192
// Attention view: (H2,W2)=(64,128). Conv view: (8, 1024). K_ATT=7 PAD=3.
//
// R6 structure: 3 dispatches (R5 fusion reverted: it spilled 256+ VGPRs ->
// 105 MB scratch writes).  This round attacks wave-level parallelism:
// every kernel was running 4 waves/CU (1 block of 256 thr per CU).
//   att : 512 thr/block, 2 thr/pixel (channel split 8/8, shfl_xor combine)
//   conv: 512 blocks (64-wide tiles) -> 2 blocks/CU

// ---------------------------------------------------------------------------
// Kernel 1: fused q/k/v 1x1 convs + fc (f_all).  (unchanged from R4/R5)
// ---------------------------------------------------------------------------
__global__ __launch_bounds__(512) void qkvf_kernel(
    const float* __restrict__ x,
    const float* __restrict__ w1, const float* __restrict__ b1,
    const float* __restrict__ w2, const float* __restrict__ b2,
    const float* __restrict__ w3, const float* __restrict__ b3,
    const float* __restrict__ wfc,
    float* __restrict__ q, float* __restrict__ k, float* __restrict__ v,
    float* __restrict__ f)
{
    __shared__ float xs[64][64];        // [ci][l]       16 KB
    __shared__ float wlds[3][64][64];   // [mat][c][ci]  48 KB

    int bx    = blockIdx.x;
    int ltile = bx & 127;
    int b     = bx >> 7;
    int l0    = ltile * 64;

    {
        float4* wl = (float4*)wlds;
        for (int t = threadIdx.x; t < 3072; t += 512) {
            int m   = t >> 10;
            int idx = t & 1023;
            const float* src = (m == 0) ? w1 : (m == 1) ? w2 : w3;
            wl[t] = ((const float4*)src)[idx];
        }
    }
    const float4* xg = (const float4*)(x + (size_t)b * 64 * 8192);
    for (int t = threadIdx.x; t < 1024; t += 512) {
        int ci = t >> 4, col = t & 15;
        *((float4*)&xs[ci][col * 4]) = xg[ci * 2048 + (l0 >> 2) + col];
    }
    __syncthreads();

    int lane = threadIdx.x & 63;
    int wv   = __builtin_amdgcn_readfirstlane(threadIdx.x >> 6);
    int l    = l0 + lane;
    int hd0  = 2 * wv;

    float qa[4][2], ka[4][2], va[4][2];
#pragma unroll
    for (int hh = 0; hh < 4; ++hh)
#pragma unroll
        for (int p = 0; p < 2; ++p) {
            int c = hh * 16 + hd0 + p;
            qa[hh][p] = b1[c]; ka[hh][p] = b2[c]; va[hh][p] = b3[c];
        }

#pragma unroll 4
    for (int c4 = 0; c4 < 16; ++c4) {
        float xv[4];
#pragma unroll
        for (int u = 0; u < 4; ++u) xv[u] = xs[c4 * 4 + u][lane];
#pragma unroll
        for (int hh = 0; hh < 4; ++hh)
#pragma unroll
            for (int p = 0; p < 2; ++p) {
                int c = hh * 16 + hd0 + p;
                float4 wq = *(const float4*)&wlds[0][c][c4 * 4];
                float4 wk = *(const float4*)&wlds[1][c][c4 * 4];
                float4 wx = *(const float4*)&wlds[2][c][c4 * 4];
                qa[hh][p] = fmaf(wq.x, xv[0], qa[hh][p]);
                qa[hh][p] = fmaf(wq.y, xv[1], qa[hh][p]);
                qa[hh][p] = fmaf(wq.z, xv[2], qa[hh][p]);
                qa[hh][p] = fmaf(wq.w, xv[3], qa[hh][p]);
                ka[hh][p] = fmaf(wk.x, xv[0], ka[hh][p]);
                ka[hh][p] = fmaf(wk.y, xv[1], ka[hh][p]);
                ka[hh][p] = fmaf(wk.z, xv[2], ka[hh][p]);
                ka[hh][p] = fmaf(wk.w, xv[3], ka[hh][p]);
                va[hh][p] = fmaf(wx.x, xv[0], va[hh][p]);
                va[hh][p] = fmaf(wx.y, xv[1], va[hh][p]);
                va[hh][p] = fmaf(wx.z, xv[2], va[hh][p]);
                va[hh][p] = fmaf(wx.w, xv[3], va[hh][p]);
            }
    }

#pragma unroll
    for (int hh = 0; hh < 4; ++hh)
#pragma unroll
        for (int p = 0; p < 2; ++p) {
            int c = hh * 16 + hd0 + p;
            size_t o = (size_t)(b * 64 + c) * 8192 + l;
            q[o] = qa[hh][p] * 0.25f;   // fold HEAD_DIM^-0.5 here
            k[o] = ka[hh][p]; v[o] = va[hh][p];
        }

#pragma unroll
    for (int m = 0; m < 9; ++m)
#pragma unroll
        for (int p = 0; p < 2; ++p) {
            float acc = 0.f;
#pragma unroll
            for (int hh = 0; hh < 4; ++hh) {
                acc = fmaf(wfc[m * 12 + 0 + hh], qa[hh][p], acc);
                acc = fmaf(wfc[m * 12 + 4 + hh], ka[hh][p], acc);
                acc = fmaf(wfc[m * 12 + 8 + hh], va[hh][p], acc);
            }
            int hd = hd0 + p;
            f[((size_t)(b * 9 + m) * 16 + hd) * 8192 + l] = acc;
        }
}

// ---------------------------------------------------------------------------
// Kernel 2: attention branch.  out = rate1 * out_att.
// 512 thr/block (8 waves/CU), 2 threads per pixel: thread part p owns
// channels 8p..8p+7.  QK partial dots combined with __shfl_xor(.,1)
// (lane-adjacent pair, DPP-cheap).  LDS [22][22][20] pad as R4 (conflict-
// minimal b128: starts (20x+8p)%32 tile all banks uniformly, 8 dw/bank).
// ---------------------------------------------------------------------------
__global__ __launch_bounds__(512, 4) void att_kernel(
    const float* __restrict__ q, const float* __restrict__ k,
    const float* __restrict__ v,
    const float* __restrict__ wp, const float* __restrict__ bp,
    const float* __restrict__ rate1p, float* __restrict__ out)
{
    __shared__ float kp[22 * 22 * 20];   // 38.7 KB
    __shared__ float vt[22 * 22 * 20];   // 38.7 KB

    int bx = blockIdx.x;          // 8 n * 4 yt * 8 xt = 256
    int xt = bx & 7;
    int yt = (bx >> 3) & 3;
    int n  = bx >> 5;
    int head = n & 3;
    int b    = n >> 2;
    int y0 = yt * 16, x0 = xt * 16;

    const int NELEM = 16 * 22 * 22;   // c slow; ty, tx fast
    for (int e = threadIdx.x; e < NELEM; e += 512) {
        int tx  = e % 22;
        int rem = e / 22;
        int ty  = rem % 22;
        int c   = rem / 22;
        int sy = y0 + ty - 3; if (sy < 0) sy = -sy; else if (sy >= 64)  sy = 126 - sy;
        int sx = x0 + tx - 3; if (sx < 0) sx = -sx; else if (sx >= 128) sx = 254 - sx;
        int l = sy * 128 + sx;
        size_t o = (size_t)(b * 64 + head * 16 + c) * 8192 + l;
        int dd = l >> 10, r2 = l & 1023, ww = r2 >> 5, hh = r2 & 31;
        float ld = dd * (2.0f / 7.0f)  - 1.0f;
        float lw = ww * (2.0f / 31.0f) - 1.0f;
        float lh = hh * (2.0f / 31.0f) - 1.0f;
        float pe = bp[c];
        pe = fmaf(wp[c * 3 + 0], ld, pe);
        pe = fmaf(wp[c * 3 + 1], lw, pe);
        pe = fmaf(wp[c * 3 + 2], lh, pe);
        int li = (ty * 22 + tx) * 20 + c;
        kp[li] = k[o] - pe;
        vt[li] = v[o];
    }
    __syncthreads();

    int pix  = threadIdx.x >> 1;      // 0..255
    int part = threadIdx.x & 1;       // channel half
    int tx = pix & 15, ty = pix >> 4;
    int l = (y0 + ty) * 128 + (x0 + tx);
    int cb = part * 8;                // channel base

    float qc[8];
#pragma unroll
    for (int c = 0; c < 8; ++c)
        qc[c] = q[(size_t)(b * 64 + head * 16 + cb + c) * 8192 + l]; // pre-scaled

    float lg[49];
#pragma unroll
    for (int i = 0; i < 7; ++i)
#pragma unroll
        for (int j = 0; j < 7; ++j) {
            const float4* p =
                (const float4*)&kp[((ty + i) * 22 + tx + j) * 20 + cb];
            float4 a = p[0], b4 = p[1];
            float acc =      qc[0] * a.x;
            acc = fmaf(qc[1], a.y,  acc); acc = fmaf(qc[2], a.z,  acc);
            acc = fmaf(qc[3], a.w,  acc); acc = fmaf(qc[4], b4.x, acc);
            acc = fmaf(qc[5], b4.y, acc); acc = fmaf(qc[6], b4.z, acc);
            acc = fmaf(qc[7], b4.w, acc);
            lg[i * 7 + j] = acc;
        }
    // combine the two channel-halves (partner = adjacent lane)
#pragma unroll
    for (int kk = 0; kk < 49; ++kk)
        lg[kk] += __shfl_xor(lg[kk], 1, 64);

    float mx = lg[0];
#pragma unroll
    for (int kk = 1; kk < 49; ++kk) mx = fmaxf(mx, lg[kk]);
    float se = 0.f;
#pragma unroll
    for (int kk = 0; kk < 49; ++kk) { lg[kk] = __expf(lg[kk] - mx); se += lg[kk]; }
    float scale = rate1p[0] / se;

    float oc[8];
#pragma unroll
    for (int c = 0; c < 8; ++c) oc[c] = 0.f;
#pragma unroll
    for (int i = 0; i < 7; ++i)
#pragma unroll
        for (int j = 0; j < 7; ++j) {
            float wgt = lg[i * 7 + j];
            const float4* p =
                (const float4*)&vt[((ty + i) * 22 + tx + j) * 20 + cb];
            float4 a = p[0], b4 = p[1];
            oc[0] = fmaf(wgt, a.x,  oc[0]); oc[1] = fmaf(wgt, a.y,  oc[1]);
            oc[2] = fmaf(wgt, a.z,  oc[2]); oc[3] = fmaf(wgt, a.w,  oc[3]);
            oc[4] = fmaf(wgt, b4.x, oc[4]); oc[5] = fmaf(wgt, b4.y, oc[5]);
            oc[6] = fmaf(wgt, b4.z, oc[6]); oc[7] = fmaf(wgt, b4.w, oc[7]);
        }

#pragma unroll
    for (int c = 0; c < 8; ++c)
        out[(size_t)(b * 64 + head * 16 + cb + c) * 8192 + l] = oc[c] * scale;
}

// ---------------------------------------------------------------------------
// Kernel 3: conv branch + combine.  out += rate2 * (depconv(f) + bdep).
// 512 blocks (64-wide x-tiles, ft 19 KB) -> 2 blocks/CU, 8 waves/CU.
// Wave w handles output channel g*4+w over 64 pixels x 8 rows.
// ---------------------------------------------------------------------------
__global__ __launch_bounds__(256) void conv_kernel(
    const float* __restrict__ f,
    const float* __restrict__ wdep, const float* __restrict__ bdep,
    const float* __restrict__ rate2p, float* __restrict__ out)
{
    __shared__ float ft[9][8][66];

    int bx = blockIdx.x;          // 2 b * 16 g * 16 xt = 512
    int xt = bx & 15;
    int g  = (bx >> 4) & 15;
    int b  = bx >> 8;
    int x0 = xt * 64;

    const int NE = 9 * 8 * 66;    // 4752
    for (int e = threadIdx.x; e < NE; e += 256) {
        int xx  = e % 66;
        int rem = e / 66;
        int y = rem % 8, i = rem / 8;
        int gx = x0 + xx - 1;
        float val = 0.f;
        if (gx >= 0 && gx < 1024) {
            int c144 = g * 9 + i;
            val = f[((size_t)(b * 144 + c144)) * 8192 + y * 1024 + gx];
        }
        ft[i][y][xx] = val;
    }
    __syncthreads();

    int xl = threadIdx.x & 63;
    int op = __builtin_amdgcn_readfirstlane(threadIdx.x >> 6); // wave id 0..3
    int o  = g * 4 + op;
    float rate2 = rate2p[0];

    float acc[8];
#pragma unroll
    for (int y = 0; y < 8; ++y) acc[y] = 0.f;

    for (int i = 0; i < 9; ++i) {
        float fr[10][3];
#pragma unroll
        for (int dx = 0; dx < 3; ++dx) { fr[0][dx] = 0.f; fr[9][dx] = 0.f; }
#pragma unroll
        for (int y = 0; y < 8; ++y)
#pragma unroll
            for (int dx = 0; dx < 3; ++dx)
                fr[y + 1][dx] = ft[i][y][xl + dx];
#pragma unroll
        for (int ky = 0; ky < 3; ++ky)
#pragma unroll
            for (int kx = 0; kx < 3; ++kx) {
                float wvv = wdep[((o * 9 + i) * 3 + ky) * 3 + kx];
#pragma unroll
                for (int y = 0; y < 8; ++y)
                    acc[y] = fmaf(wvv, fr[y + ky][kx], acc[y]);
            }
    }

    float bd = bdep[o];
#pragma unroll
    for (int y = 0; y < 8; ++y) {
        size_t idx = (size_t)(b * 64 + o) * 8192 + y * 1024 + x0 + xl;
        out[idx] = out[idx] + rate2 * (acc[y] + bd);
    }
}

// ---------------------------------------------------------------------------
extern "C" void kernel_launch(void* const* d_in, const int* in_sizes, int n_in,
                              void* d_out, int out_size, void* d_ws, size_t ws_size,
                              hipStream_t stream)
{
    (void)in_sizes; (void)n_in; (void)out_size; (void)ws_size;
    const float* x     = (const float*)d_in[0];
    const float* w1    = (const float*)d_in[1];
    const float* b1    = (const float*)d_in[2];
    const float* w2    = (const float*)d_in[3];
    const float* b2    = (const float*)d_in[4];
    const float* w3    = (const float*)d_in[5];
    const float* b3    = (const float*)d_in[6];
    const float* wp    = (const float*)d_in[7];
    const float* bp    = (const float*)d_in[8];
    const float* wfc   = (const float*)d_in[9];
    const float* wdep  = (const float*)d_in[10];
    const float* bdep  = (const float*)d_in[11];
    const float* rate1 = (const float*)d_in[12];
    const float* rate2 = (const float*)d_in[13];
    float* out = (float*)d_out;

    float* wsf = (float*)d_ws;
    float* q = wsf;                 // 3 x 1,048,576 floats (q,k,v)
    float* k = wsf + 1048576;
    float* v = wsf + 2097152;
    float* f = wsf + 3145728;       // 2,359,296 floats

    qkvf_kernel<<<256, 512, 0, stream>>>(x, w1, b1, w2, b2, w3, b3, wfc,
                                         q, k, v, f);
    att_kernel <<<256, 512, 0, stream>>>(q, k, v, wp, bp, rate1, out);
    conv_kernel<<<512, 256, 0, stream>>>(f, wdep, bdep, rate2, out);
}

// Round 7
// 120.168 us; speedup vs baseline: 1.5558x; 1.0579x over previous
//
#include <hip/hip_runtime.h>

// ACmix: b=2, C=64 (HEAD=4 x HEAD_DIM=16), (d,w,h)=(8,32,32), L=8192
// Attention view: (H2,W2)=(64,128). Conv view: (8, 1024). K_ATT=7 PAD=3.
//
// R7: qkvf restructured for LDS-instruction economy.
//   grid 256 = b(2) x ltile(64 tiles of 128 l) x hd-half(2).
//   Wave owns ONE hd (4 channel-triples, 12 streams); thread owns 2 l.
//   Per wave: 192 weight ds_read_b128 for 3072 FMA (16 FMA/read, was 4).
//   Block stages only its 32 channels' weights (24 KB) + x tile (32 KB).
// att (512 thr) / conv (512 blocks) unchanged from R6.

// ---------------------------------------------------------------------------
// Kernel 1: fused q/k/v 1x1 convs + fc (f_all).
// ---------------------------------------------------------------------------
__global__ __launch_bounds__(512) void qkvf_kernel(
    const float* __restrict__ x,
    const float* __restrict__ w1, const float* __restrict__ b1,
    const float* __restrict__ w2, const float* __restrict__ b2,
    const float* __restrict__ w3, const float* __restrict__ b3,
    const float* __restrict__ wfc,
    float* __restrict__ q, float* __restrict__ k, float* __restrict__ v,
    float* __restrict__ f)
{
    __shared__ float xs[64][128];       // [ci][l]            32 KB
    __shared__ float wlds[3][32][64];   // [mat][c_local][ci] 24 KB

    int bx    = blockIdx.x;            // 256 = b*2 + half*? : see below
    int ltile = bx & 63;
    int half  = (bx >> 6) & 1;
    int b     = bx >> 7;
    int l0    = ltile * 128;
    int hdb   = half * 8;

    // ---- stage weights: 1536 float4 (this half's 32 channels x 3 mats) ----
    for (int t = threadIdx.x; t < 1536; t += 512) {
        int mat = t >> 9;              // 512 f4 per mat
        int r   = t & 511;
        int cl  = r >> 4;              // c_local 0..31
        int col = r & 15;
        int hh = cl >> 3, hdl = cl & 7;
        int c  = hh * 16 + hdb + hdl;
        const float* src = (mat == 0) ? w1 : (mat == 1) ? w2 : w3;
        ((float4*)wlds)[t] = ((const float4*)src)[c * 16 + col];
    }
    // ---- stage x tile: 2048 float4 (64 ci x 128 l) ----
    const float4* xg = (const float4*)(x + (size_t)b * 64 * 8192);
    for (int t = threadIdx.x; t < 2048; t += 512) {
        int ci = t >> 5, col = t & 31;
        ((float4*)xs)[t] = xg[ci * 2048 + (l0 >> 2) + col];
    }
    __syncthreads();

    int lane = threadIdx.x & 63;
    int wv   = __builtin_amdgcn_readfirstlane(threadIdx.x >> 6); // 0..7
    int hd   = hdb + wv;               // wave-uniform hd
    int ll   = 2 * lane;               // local l offset (thread owns ll, ll+1)

    float qa[4][2], ka[4][2], va[4][2];
#pragma unroll
    for (int hh = 0; hh < 4; ++hh) {
        int c = hh * 16 + hd;
        qa[hh][0] = qa[hh][1] = b1[c];
        ka[hh][0] = ka[hh][1] = b2[c];
        va[hh][0] = va[hh][1] = b3[c];
    }

#pragma unroll 4
    for (int c4 = 0; c4 < 16; ++c4) {
        float2 xv[4];
#pragma unroll
        for (int u = 0; u < 4; ++u)
            xv[u] = *(const float2*)&xs[c4 * 4 + u][ll];
#pragma unroll
        for (int hh = 0; hh < 4; ++hh) {
            int cl = hh * 8 + wv;
            float4 wq = *(const float4*)&wlds[0][cl][c4 * 4];
            float4 wk = *(const float4*)&wlds[1][cl][c4 * 4];
            float4 wx = *(const float4*)&wlds[2][cl][c4 * 4];
            qa[hh][0] = fmaf(wq.x, xv[0].x, qa[hh][0]);
            qa[hh][1] = fmaf(wq.x, xv[0].y, qa[hh][1]);
            qa[hh][0] = fmaf(wq.y, xv[1].x, qa[hh][0]);
            qa[hh][1] = fmaf(wq.y, xv[1].y, qa[hh][1]);
            qa[hh][0] = fmaf(wq.z, xv[2].x, qa[hh][0]);
            qa[hh][1] = fmaf(wq.z, xv[2].y, qa[hh][1]);
            qa[hh][0] = fmaf(wq.w, xv[3].x, qa[hh][0]);
            qa[hh][1] = fmaf(wq.w, xv[3].y, qa[hh][1]);

            ka[hh][0] = fmaf(wk.x, xv[0].x, ka[hh][0]);
            ka[hh][1] = fmaf(wk.x, xv[0].y, ka[hh][1]);
            ka[hh][0] = fmaf(wk.y, xv[1].x, ka[hh][0]);
            ka[hh][1] = fmaf(wk.y, xv[1].y, ka[hh][1]);
            ka[hh][0] = fmaf(wk.z, xv[2].x, ka[hh][0]);
            ka[hh][1] = fmaf(wk.z, xv[2].y, ka[hh][1]);
            ka[hh][0] = fmaf(wk.w, xv[3].x, ka[hh][0]);
            ka[hh][1] = fmaf(wk.w, xv[3].y, ka[hh][1]);

            va[hh][0] = fmaf(wx.x, xv[0].x, va[hh][0]);
            va[hh][1] = fmaf(wx.x, xv[0].y, va[hh][1]);
            va[hh][0] = fmaf(wx.y, xv[1].x, va[hh][0]);
            va[hh][1] = fmaf(wx.y, xv[1].y, va[hh][1]);
            va[hh][0] = fmaf(wx.z, xv[2].x, va[hh][0]);
            va[hh][1] = fmaf(wx.z, xv[2].y, va[hh][1]);
            va[hh][0] = fmaf(wx.w, xv[3].x, va[hh][0]);
            va[hh][1] = fmaf(wx.w, xv[3].y, va[hh][1]);
        }
    }

    // ---- stores: q (pre-scaled), k, v as float2 (lane stride 8 B) ----
#pragma unroll
    for (int hh = 0; hh < 4; ++hh) {
        int c = hh * 16 + hd;
        size_t o = (size_t)(b * 64 + c) * 8192 + l0 + ll;
        *(float2*)&q[o] = make_float2(qa[hh][0] * 0.25f, qa[hh][1] * 0.25f);
        *(float2*)&k[o] = make_float2(ka[hh][0], ka[hh][1]);
        *(float2*)&v[o] = make_float2(va[hh][0], va[hh][1]);
    }

    // ---- f_all for this wave's hd: 9 m x 2 l ----
#pragma unroll
    for (int m = 0; m < 9; ++m) {
        float a0 = 0.f, a1 = 0.f;
#pragma unroll
        for (int hh = 0; hh < 4; ++hh) {
            a0 = fmaf(wfc[m * 12 + 0 + hh], qa[hh][0], a0);
            a1 = fmaf(wfc[m * 12 + 0 + hh], qa[hh][1], a1);
            a0 = fmaf(wfc[m * 12 + 4 + hh], ka[hh][0], a0);
            a1 = fmaf(wfc[m * 12 + 4 + hh], ka[hh][1], a1);
            a0 = fmaf(wfc[m * 12 + 8 + hh], va[hh][0], a0);
            a1 = fmaf(wfc[m * 12 + 8 + hh], va[hh][1], a1);
        }
        size_t o = ((size_t)(b * 9 + m) * 16 + hd) * 8192 + l0 + ll;
        *(float2*)&f[o] = make_float2(a0, a1);
    }
}

// ---------------------------------------------------------------------------
// Kernel 2: attention branch.  out = rate1 * out_att.  (unchanged from R6)
// 512 thr/block, 2 threads per pixel (channel split 8/8, shfl_xor combine).
// LDS [22][22][20] pad = conflict-minimal b128.
// ---------------------------------------------------------------------------
__global__ __launch_bounds__(512, 4) void att_kernel(
    const float* __restrict__ q, const float* __restrict__ k,
    const float* __restrict__ v,
    const float* __restrict__ wp, const float* __restrict__ bp,
    const float* __restrict__ rate1p, float* __restrict__ out)
{
    __shared__ float kp[22 * 22 * 20];   // 38.7 KB
    __shared__ float vt[22 * 22 * 20];   // 38.7 KB

    int bx = blockIdx.x;          // 8 n * 4 yt * 8 xt = 256
    int xt = bx & 7;
    int yt = (bx >> 3) & 3;
    int n  = bx >> 5;
    int head = n & 3;
    int b    = n >> 2;
    int y0 = yt * 16, x0 = xt * 16;

    const int NELEM = 16 * 22 * 22;   // c slow; ty, tx fast
    for (int e = threadIdx.x; e < NELEM; e += 512) {
        int tx  = e % 22;
        int rem = e / 22;
        int ty  = rem % 22;
        int c   = rem / 22;
        int sy = y0 + ty - 3; if (sy < 0) sy = -sy; else if (sy >= 64)  sy = 126 - sy;
        int sx = x0 + tx - 3; if (sx < 0) sx = -sx; else if (sx >= 128) sx = 254 - sx;
        int l = sy * 128 + sx;
        size_t o = (size_t)(b * 64 + head * 16 + c) * 8192 + l;
        int dd = l >> 10, r2 = l & 1023, ww = r2 >> 5, hh = r2 & 31;
        float ld = dd * (2.0f / 7.0f)  - 1.0f;
        float lw = ww * (2.0f / 31.0f) - 1.0f;
        float lh = hh * (2.0f / 31.0f) - 1.0f;
        float pe = bp[c];
        pe = fmaf(wp[c * 3 + 0], ld, pe);
        pe = fmaf(wp[c * 3 + 1], lw, pe);
        pe = fmaf(wp[c * 3 + 2], lh, pe);
        int li = (ty * 22 + tx) * 20 + c;
        kp[li] = k[o] - pe;
        vt[li] = v[o];
    }
    __syncthreads();

    int pix  = threadIdx.x >> 1;      // 0..255
    int part = threadIdx.x & 1;       // channel half
    int tx = pix & 15, ty = pix >> 4;
    int l = (y0 + ty) * 128 + (x0 + tx);
    int cb = part * 8;                // channel base

    float qc[8];
#pragma unroll
    for (int c = 0; c < 8; ++c)
        qc[c] = q[(size_t)(b * 64 + head * 16 + cb + c) * 8192 + l]; // pre-scaled

    float lg[49];
#pragma unroll
    for (int i = 0; i < 7; ++i)
#pragma unroll
        for (int j = 0; j < 7; ++j) {
            const float4* p =
                (const float4*)&kp[((ty + i) * 22 + tx + j) * 20 + cb];
            float4 a = p[0], b4 = p[1];
            float acc =      qc[0] * a.x;
            acc = fmaf(qc[1], a.y,  acc); acc = fmaf(qc[2], a.z,  acc);
            acc = fmaf(qc[3], a.w,  acc); acc = fmaf(qc[4], b4.x, acc);
            acc = fmaf(qc[5], b4.y, acc); acc = fmaf(qc[6], b4.z, acc);
            acc = fmaf(qc[7], b4.w, acc);
            lg[i * 7 + j] = acc;
        }
#pragma unroll
    for (int kk = 0; kk < 49; ++kk)
        lg[kk] += __shfl_xor(lg[kk], 1, 64);

    float mx = lg[0];
#pragma unroll
    for (int kk = 1; kk < 49; ++kk) mx = fmaxf(mx, lg[kk]);
    float se = 0.f;
#pragma unroll
    for (int kk = 0; kk < 49; ++kk) { lg[kk] = __expf(lg[kk] - mx); se += lg[kk]; }
    float scale = rate1p[0] / se;

    float oc[8];
#pragma unroll
    for (int c = 0; c < 8; ++c) oc[c] = 0.f;
#pragma unroll
    for (int i = 0; i < 7; ++i)
#pragma unroll
        for (int j = 0; j < 7; ++j) {
            float wgt = lg[i * 7 + j];
            const float4* p =
                (const float4*)&vt[((ty + i) * 22 + tx + j) * 20 + cb];
            float4 a = p[0], b4 = p[1];
            oc[0] = fmaf(wgt, a.x,  oc[0]); oc[1] = fmaf(wgt, a.y,  oc[1]);
            oc[2] = fmaf(wgt, a.z,  oc[2]); oc[3] = fmaf(wgt, a.w,  oc[3]);
            oc[4] = fmaf(wgt, b4.x, oc[4]); oc[5] = fmaf(wgt, b4.y, oc[5]);
            oc[6] = fmaf(wgt, b4.z, oc[6]); oc[7] = fmaf(wgt, b4.w, oc[7]);
        }

#pragma unroll
    for (int c = 0; c < 8; ++c)
        out[(size_t)(b * 64 + head * 16 + cb + c) * 8192 + l] = oc[c] * scale;
}

// ---------------------------------------------------------------------------
// Kernel 3: conv branch + combine.  (unchanged from R6)
// 512 blocks (64-wide x-tiles, ft 19 KB) -> 2 blocks/CU, 8 waves/CU.
// ---------------------------------------------------------------------------
__global__ __launch_bounds__(256) void conv_kernel(
    const float* __restrict__ f,
    const float* __restrict__ wdep, const float* __restrict__ bdep,
    const float* __restrict__ rate2p, float* __restrict__ out)
{
    __shared__ float ft[9][8][66];

    int bx = blockIdx.x;          // 2 b * 16 g * 16 xt = 512
    int xt = bx & 15;
    int g  = (bx >> 4) & 15;
    int b  = bx >> 8;
    int x0 = xt * 64;

    const int NE = 9 * 8 * 66;    // 4752
    for (int e = threadIdx.x; e < NE; e += 256) {
        int xx  = e % 66;
        int rem = e / 66;
        int y = rem % 8, i = rem / 8;
        int gx = x0 + xx - 1;
        float val = 0.f;
        if (gx >= 0 && gx < 1024) {
            int c144 = g * 9 + i;
            val = f[((size_t)(b * 144 + c144)) * 8192 + y * 1024 + gx];
        }
        ft[i][y][xx] = val;
    }
    __syncthreads();

    int xl = threadIdx.x & 63;
    int op = __builtin_amdgcn_readfirstlane(threadIdx.x >> 6); // wave id 0..3
    int o  = g * 4 + op;
    float rate2 = rate2p[0];

    float acc[8];
#pragma unroll
    for (int y = 0; y < 8; ++y) acc[y] = 0.f;

    for (int i = 0; i < 9; ++i) {
        float fr[10][3];
#pragma unroll
        for (int dx = 0; dx < 3; ++dx) { fr[0][dx] = 0.f; fr[9][dx] = 0.f; }
#pragma unroll
        for (int y = 0; y < 8; ++y)
#pragma unroll
            for (int dx = 0; dx < 3; ++dx)
                fr[y + 1][dx] = ft[i][y][xl + dx];
#pragma unroll
        for (int ky = 0; ky < 3; ++ky)
#pragma unroll
            for (int kx = 0; kx < 3; ++kx) {
                float wvv = wdep[((o * 9 + i) * 3 + ky) * 3 + kx];
#pragma unroll
                for (int y = 0; y < 8; ++y)
                    acc[y] = fmaf(wvv, fr[y + ky][kx], acc[y]);
            }
    }

    float bd = bdep[o];
#pragma unroll
    for (int y = 0; y < 8; ++y) {
        size_t idx = (size_t)(b * 64 + o) * 8192 + y * 1024 + x0 + xl;
        out[idx] = out[idx] + rate2 * (acc[y] + bd);
    }
}

// ---------------------------------------------------------------------------
extern "C" void kernel_launch(void* const* d_in, const int* in_sizes, int n_in,
                              void* d_out, int out_size, void* d_ws, size_t ws_size,
                              hipStream_t stream)
{
    (void)in_sizes; (void)n_in; (void)out_size; (void)ws_size;
    const float* x     = (const float*)d_in[0];
    const float* w1    = (const float*)d_in[1];
    const float* b1    = (const float*)d_in[2];
    const float* w2    = (const float*)d_in[3];
    const float* b2    = (const float*)d_in[4];
    const float* w3    = (const float*)d_in[5];
    const float* b3    = (const float*)d_in[6];
    const float* wp    = (const float*)d_in[7];
    const float* bp    = (const float*)d_in[8];
    const float* wfc   = (const float*)d_in[9];
    const float* wdep  = (const float*)d_in[10];
    const float* bdep  = (const float*)d_in[11];
    const float* rate1 = (const float*)d_in[12];
    const float* rate2 = (const float*)d_in[13];
    float* out = (float*)d_out;

    float* wsf = (float*)d_ws;
    float* q = wsf;                 // 3 x 1,048,576 floats (q,k,v)
    float* k = wsf + 1048576;
    float* v = wsf + 2097152;
    float* f = wsf + 3145728;       // 2,359,296 floats

    qkvf_kernel<<<256, 512, 0, stream>>>(x, w1, b1, w2, b2, w3, b3, wfc,
                                         q, k, v, f);
    att_kernel <<<256, 512, 0, stream>>>(q, k, v, wp, bp, rate1, out);
    conv_kernel<<<512, 256, 0, stream>>>(f, wdep, bdep, rate2, out);
}